// Round 2
// baseline (75.264 us; speedup 1.0000x reference)
//
#include <hip/hip_runtime.h>

#define N_ATOMS 8388608
#define N_MOLS  262144

// Pass 1: per-atom loads; wave-level segmented scan (mol_id is sorted, so
// mol equality with lane-offset implies the whole intervening range is the
// same molecule); segment-tail lanes do the atomic adds.
__global__ __launch_bounds__(256) void ce_pass1(
    const float2* __restrict__ h, const float* __restrict__ q,
    const int* __restrict__ mol,
    float* __restrict__ sum_q, float* __restrict__ sum_si,
    float* __restrict__ sum_esi)
{
    int i = blockIdx.x * blockDim.x + threadIdx.x;
    float2 hv = h[i];
    float qi = q[i];
    int m = mol[i];
    float si = 1.0f / hv.y;
    float esi = hv.x * si;

    int lane = threadIdx.x & 63;
    float vq = qi, vs = si, ve = esi;
    #pragma unroll
    for (int off = 1; off < 64; off <<= 1) {
        int   om = __shfl_up(m,  off, 64);
        float oq = __shfl_up(vq, off, 64);
        float os = __shfl_up(vs, off, 64);
        float oe = __shfl_up(ve, off, 64);
        if (lane >= off && om == m) { vq += oq; vs += os; ve += oe; }
    }
    int nm = __shfl_down(m, 1, 64);
    bool tail = (lane == 63) || (nm != m);
    if (tail) {
        atomicAdd(&sum_q[m],   vq);
        atomicAdd(&sum_si[m],  vs);
        atomicAdd(&sum_esi[m], ve);
    }
}

// Pass 2: per-molecule combine: t = (sum_q + sum_esi) / sum_si
__global__ __launch_bounds__(256) void ce_pass2(
    const float* __restrict__ sum_q, const float* __restrict__ sum_si,
    const float* __restrict__ sum_esi, float* __restrict__ t)
{
    int mID = blockIdx.x * blockDim.x + threadIdx.x;
    t[mID] = (sum_q[mID] + sum_esi[mID]) / sum_si[mID];
}

// Pass 3: per-atom output: q_hat = s_inv * (t[mol] - e)
__global__ __launch_bounds__(256) void ce_pass3(
    const float2* __restrict__ h, const int* __restrict__ mol,
    const float* __restrict__ t, float* __restrict__ out)
{
    int i = blockIdx.x * blockDim.x + threadIdx.x;
    float2 hv = h[i];
    float si = 1.0f / hv.y;
    out[i] = si * (t[mol[i]] - hv.x);
}

extern "C" void kernel_launch(void* const* d_in, const int* in_sizes, int n_in,
                              void* d_out, int out_size, void* d_ws, size_t ws_size,
                              hipStream_t stream) {
    const float2* h  = (const float2*)d_in[0];
    const float*  q  = (const float*)d_in[1];
    const int*    mol = (const int*)d_in[2];
    float* out = (float*)d_out;

    float* sum_q   = (float*)d_ws;
    float* sum_si  = sum_q  + N_MOLS;
    float* sum_esi = sum_si + N_MOLS;
    float* t       = sum_esi + N_MOLS;

    // zero the accumulators every call (harness poisons ws once, never again)
    hipMemsetAsync(d_ws, 0, (size_t)3 * N_MOLS * sizeof(float), stream);

    ce_pass1<<<N_ATOMS / 256, 256, 0, stream>>>(h, q, mol, sum_q, sum_si, sum_esi);
    ce_pass2<<<N_MOLS / 256, 256, 0, stream>>>(sum_q, sum_si, sum_esi, t);
    ce_pass3<<<N_ATOMS / 256, 256, 0, stream>>>(h, mol, t, out);
}

// Round 3
// 62.100 us; speedup vs baseline: 1.2120x; 1.2120x over previous
//
#include <hip/hip_runtime.h>

#define N_ATOMS 8388608
#define N_MOLS  262144
// 8 atoms per thread, 256 threads/block
#define P1_BLOCKS (N_ATOMS / (256 * 8))

// Pass 1: 8 atoms/thread. Serial in-register segment accumulate (interior
// molecule boundaries flushed via atomics — rare, ~262K total), then a
// wave-level segmented inclusive scan over per-thread TAIL partials.
// mol_id sorted => equal tail keys across lanes are a contiguous run, so the
// Hillis-Steele equal-key scan is exact; segment-tail lanes flush.
__global__ __launch_bounds__(256) void ce_pass1(
    const float4* __restrict__ h4,   // 2 atoms per float4 (e,s,e,s)
    const float4* __restrict__ q4,   // 4 atoms per float4
    const int4*  __restrict__ mol4,  // 4 atoms per int4
    float* __restrict__ sum_q, float* __restrict__ sum_si,
    float* __restrict__ sum_esi)
{
    int t = blockIdx.x * blockDim.x + threadIdx.x;

    float4 ha = h4[t * 4 + 0], hb = h4[t * 4 + 1];
    float4 hc = h4[t * 4 + 2], hd = h4[t * 4 + 3];
    float4 qa = q4[t * 2 + 0], qb = q4[t * 2 + 1];
    int4   ma = mol4[t * 2 + 0], mb = mol4[t * 2 + 1];

    float e[8]  = {ha.x, ha.z, hb.x, hb.z, hc.x, hc.z, hd.x, hd.z};
    float s[8]  = {ha.y, ha.w, hb.y, hb.w, hc.y, hc.w, hd.y, hd.w};
    float qq[8] = {qa.x, qa.y, qa.z, qa.w, qb.x, qb.y, qb.z, qb.w};
    int   mm[8] = {ma.x, ma.y, ma.z, ma.w, mb.x, mb.y, mb.z, mb.w};

    int   mcur = mm[0];
    float aq = 0.f, as = 0.f, ae = 0.f;
    #pragma unroll
    for (int k = 0; k < 8; ++k) {
        float si  = 1.0f / s[k];
        float esi = e[k] * si;
        if (mm[k] != mcur) {   // rare: ~3% of iterations
            atomicAdd(&sum_q[mcur],   aq);
            atomicAdd(&sum_si[mcur],  as);
            atomicAdd(&sum_esi[mcur], ae);
            mcur = mm[k]; aq = 0.f; as = 0.f; ae = 0.f;
        }
        aq += qq[k]; as += si; ae += esi;
    }

    int lane = threadIdx.x & 63;
    #pragma unroll
    for (int off = 1; off < 64; off <<= 1) {
        int   om = __shfl_up(mcur, off, 64);
        float oq = __shfl_up(aq,  off, 64);
        float os = __shfl_up(as,  off, 64);
        float oe = __shfl_up(ae,  off, 64);
        if (lane >= off && om == mcur) { aq += oq; as += os; ae += oe; }
    }
    int nm = __shfl_down(mcur, 1, 64);
    if (lane == 63 || nm != mcur) {
        atomicAdd(&sum_q[mcur],   aq);
        atomicAdd(&sum_si[mcur],  as);
        atomicAdd(&sum_esi[mcur], ae);
    }
}

// Pass 2: per-molecule combine: t = (sum_q + sum_esi) / sum_si
__global__ __launch_bounds__(256) void ce_pass2(
    const float* __restrict__ sum_q, const float* __restrict__ sum_si,
    const float* __restrict__ sum_esi, float* __restrict__ t)
{
    int m = blockIdx.x * blockDim.x + threadIdx.x;
    t[m] = (sum_q[m] + sum_esi[m]) / sum_si[m];
}

// Pass 3: 8 atoms/thread: out = s_inv * (t[mol] - e); t gather is sorted
// (broadcast within wave) and L2-resident (1 MB).
__global__ __launch_bounds__(256) void ce_pass3(
    const float4* __restrict__ h4, const int4* __restrict__ mol4,
    const float* __restrict__ t, float4* __restrict__ out4)
{
    int tid = blockIdx.x * blockDim.x + threadIdx.x;

    float4 ha = h4[tid * 4 + 0], hb = h4[tid * 4 + 1];
    float4 hc = h4[tid * 4 + 2], hd = h4[tid * 4 + 3];
    int4   ma = mol4[tid * 2 + 0], mb = mol4[tid * 2 + 1];

    float4 o0, o1;
    o0.x = (1.0f / ha.y) * (t[ma.x] - ha.x);
    o0.y = (1.0f / ha.w) * (t[ma.y] - ha.z);
    o0.z = (1.0f / hb.y) * (t[ma.z] - hb.x);
    o0.w = (1.0f / hb.w) * (t[ma.w] - hb.z);
    o1.x = (1.0f / hc.y) * (t[mb.x] - hc.x);
    o1.y = (1.0f / hc.w) * (t[mb.y] - hc.z);
    o1.z = (1.0f / hd.y) * (t[mb.z] - hd.x);
    o1.w = (1.0f / hd.w) * (t[mb.w] - hd.z);

    out4[tid * 2 + 0] = o0;
    out4[tid * 2 + 1] = o1;
}

extern "C" void kernel_launch(void* const* d_in, const int* in_sizes, int n_in,
                              void* d_out, int out_size, void* d_ws, size_t ws_size,
                              hipStream_t stream) {
    const float4* h4   = (const float4*)d_in[0];
    const float4* q4   = (const float4*)d_in[1];
    const int4*   mol4 = (const int4*)d_in[2];
    float4* out4 = (float4*)d_out;

    float* sum_q   = (float*)d_ws;
    float* sum_si  = sum_q  + N_MOLS;
    float* sum_esi = sum_si + N_MOLS;
    float* t       = sum_esi + N_MOLS;

    hipMemsetAsync(d_ws, 0, (size_t)3 * N_MOLS * sizeof(float), stream);

    ce_pass1<<<P1_BLOCKS, 256, 0, stream>>>(h4, (const float4*)d_in[1],
                                            mol4, sum_q, sum_si, sum_esi);
    ce_pass2<<<N_MOLS / 256, 256, 0, stream>>>(sum_q, sum_si, sum_esi, t);
    ce_pass3<<<P1_BLOCKS, 256, 0, stream>>>(h4, mol4, t, out4);
}